// Round 8
// baseline (96.214 us; speedup 1.0000x reference)
//
#include <hip/hip_runtime.h>
#include <cmath>

// BKT forward, B independent students, serial T-step fp32 recurrence.
//
// NUMERICS (R1-R3): harness validates vs fp32 numpy recompute; recurrence
// amplifies rounding ~2e5x over 512 steps -> must replicate np's fp32 op
// order exactly (no FMA contraction, separate rounded mul/add/div, fp64
// sigmoid rounded once). Passing absmax = 0.0039. DO NOT reassociate.
//
// PERF history:
//  R3: per-step scattered stores -> WRITE 1.05 GB (3.9x), 268 us
//  R4: reg-buffered stores, compiler sank them (VGPR=32) -> 437 MB, 153 us
//  R5: __launch_bounds__(256,1) freed regs -> 122 us
//  R6: LDS-transpose store phase, full 128B-line stores -> 90 us
//  R7: STEPS 64 (page-activation theory) -> 90 us NULL. Refuted.
//  R8 (this): fine-grained VMEM interleave. Structurally 1 wave/SIMD (grid
//      = 65536 thr = 1024 waves = #SIMDs) -> no TLP. Clustered store bursts
//      let the CU store queue DRAIN EMPTY during each 2.2us compute phase
//      (HBM idles), then stall at issue with nothing behind to overlap ->
//      serialized mem+compute = ~90us vs 64us HBM floor. Fix: one
//      (ds_read -> global_store) of chunk o-1 between every 2 compute steps
//      of chunk o, one y-load per 4 steps: in-order issue overlaps compute
//      with the NEXT store's queue-space wait; HBM queue never empties.
//      LDS single buffer [256 thr][64 f]: slots 0-7 = cr, 8-15 = lt,
//      XOR-swizzle within 8 -> conflict-free b128 write (lane=row) and
//      read (8 rows x 8 slots = full 128B/row global store lines).

__device__ __forceinline__ int comp4(const int4& v, int c) {
    return c == 0 ? v.x : c == 1 ? v.y : c == 2 ? v.z : v.w;
}

__global__ __launch_bounds__(256, 1) void bkt_fwd(
    const int* __restrict__ X,          // (B,4) int32 indices
    const int* __restrict__ Y,          // (B,T) int32 observations {0,1}
    const float* __restrict__ learn_w,  // (N,1)
    const float* __restrict__ guess_w,
    const float* __restrict__ slip_w,
    const float* __restrict__ prior_w,
    float* __restrict__ out,            // corrects (B,T) then latents (B,T)
    int B, int T)                       // requires B % 256 == 0, T % 32 == 0
{
#pragma clang fp contract(off)
    const int tid = threadIdx.x;
    const int b = blockIdx.x * 256 + tid;

    __shared__ float xp[256 * 64];      // 64 KB: per-thread 16 x 16B slots

    const int4 xi = *reinterpret_cast<const int4*>(X + (size_t)b * 4);
    // correctly-rounded fp32 sigmoids via fp64
    const float l = (float)(1.0 / (1.0 + exp(-(double)learn_w[xi.x])));
    const float g = (float)(1.0 / (1.0 + exp(-(double)guess_w[xi.y])));
    const float s = (float)(1.0 / (1.0 + exp(-(double)slip_w[xi.z])));
    const float p = (float)(1.0 / (1.0 + exp(-(double)prior_w[xi.w])));

    const float oms = 1.0f - s;              // (1-s)
    const float omg = 1.0f - g;              // (1-g)
    const float lo  = 1e-6f;
    const float hi  = (float)(1.0 - 1e-6);   // fp32(1-EPS)
    float latent = p;

    const int4* __restrict__ yv = reinterpret_cast<const int4*>(Y + (size_t)b * T);

    // transpose-store mapping: store instr q covers 8 rows (wv*64+q*8+r8),
    // 8 lanes per row covering that row's full 128B chunk (s8 = 16B slot).
    const int wv = tid >> 6, ln = tid & 63;
    const int r8 = ln >> 3;                  // 0..7
    const int s8 = ln & 7;                   // 0..7
    float* __restrict__ gcoB = out + (size_t)(blockIdx.x * 256 + wv * 64 + r8) * T + s8 * 4;
    float* __restrict__ glaB = gcoB + (size_t)B * T;

    constexpr int STEPS = 32, NQ = 8;
    const int nOuter = T / STEPS;            // 16

    int4 yq[NQ], yqn[NQ];
    #pragma unroll
    for (int q = 0; q < NQ; ++q) yq[q] = yv[q];

    for (int o = 0; o < nOuter; ++o) {
        const bool hasPrev = (o > 0);
        const bool hasNext = (o + 1 < nOuter);
        const int colPrev = (o - 1) * STEPS;

        float cr[STEPS], lt[STEPS];
        #pragma unroll
        for (int j = 0; j < STEPS; ++j) {
            // --- interleaved VMEM: keep the HBM queue fed continuously ---
            if ((j & 3) == 0 && hasNext)
                yqn[j >> 2] = yv[(o + 1) * NQ + (j >> 2)];

            // --- compute step j: EXACT np fp32 op order (do not touch) ---
            const float a       = latent * oms;       // latent*(1-s)
            const float omlat   = 1.0f - latent;      // (1-latent)
            const float t1      = omlat * g;          // (1-latent)*g
            const float correct = a + t1;
            const float n0      = latent * s;         // latent*s
            const float t2      = omlat * omg;        // (1-latent)*(1-g)
            const float d0      = n0 + t2;
            const bool hit = comp4(yq[j >> 2], j & 3) > 0;   // y_t > 0.5
            const float num = hit ? a : n0;
            const float den = hit ? correct : d0;
            const float k   = num / den;              // IEEE fp32 divide
            cr[j] = correct;
            lt[j] = latent;                           // recorded BEFORE update
            const float omk = 1.0f - k;
            const float t3  = omk * l;                // (1-k)*l
            const float nxt = k + t3;                 // k + (1-k)*l
            latent = fminf(fmaxf(nxt, lo), hi);       // clip

            // --- interleaved store of chunk o-1 (1 per 2 steps) ---
            if ((j & 1) == 1 && hasPrev) {
                const int idx = j >> 1;               // 0..15
                if (idx < NQ) {                       // corrects q = idx
                    const int q  = idx;
                    const int rl = wv * 64 + q * 8 + r8;
                    const float4 v = *reinterpret_cast<const float4*>(
                        xp + rl * 64 + ((s8 ^ (rl & 7)) << 2));
                    *reinterpret_cast<float4*>(gcoB + (size_t)(q * 8) * T + colPrev) = v;
                } else {                              // latents q = idx-8
                    const int q  = idx - NQ;
                    const int rl = wv * 64 + q * 8 + r8;
                    const float4 v = *reinterpret_cast<const float4*>(
                        xp + rl * 64 + ((8 + (s8 ^ (rl & 7))) << 2));
                    *reinterpret_cast<float4*>(glaB + (size_t)(q * 8) * T + colPrev) = v;
                }
            }
        }

        __builtin_amdgcn_wave_barrier();   // reads of o-1 precede overwrite
        #pragma unroll
        for (int q = 0; q < NQ; ++q)       // cr -> slots 0..7 (swizzled)
            *reinterpret_cast<float4*>(xp + tid * 64 + ((q ^ (tid & 7)) << 2)) =
                make_float4(cr[4*q], cr[4*q+1], cr[4*q+2], cr[4*q+3]);
        #pragma unroll
        for (int q = 0; q < NQ; ++q)       // lt -> slots 8..15 (swizzled)
            *reinterpret_cast<float4*>(xp + tid * 64 + ((8 + (q ^ (tid & 7))) << 2)) =
                make_float4(lt[4*q], lt[4*q+1], lt[4*q+2], lt[4*q+3]);
        __builtin_amdgcn_wave_barrier();

        if (hasNext) {
            #pragma unroll
            for (int q = 0; q < NQ; ++q) yq[q] = yqn[q];
        }
    }

    // epilogue: store the final chunk (o = nOuter-1)
    const int colLast = (nOuter - 1) * STEPS;
    #pragma unroll
    for (int q = 0; q < NQ; ++q) {
        const int rl = wv * 64 + q * 8 + r8;
        const float4 v = *reinterpret_cast<const float4*>(
            xp + rl * 64 + ((s8 ^ (rl & 7)) << 2));
        *reinterpret_cast<float4*>(gcoB + (size_t)(q * 8) * T + colLast) = v;
    }
    #pragma unroll
    for (int q = 0; q < NQ; ++q) {
        const int rl = wv * 64 + q * 8 + r8;
        const float4 v = *reinterpret_cast<const float4*>(
            xp + rl * 64 + ((8 + (s8 ^ (rl & 7))) << 2));
        *reinterpret_cast<float4*>(glaB + (size_t)(q * 8) * T + colLast) = v;
    }
}

extern "C" void kernel_launch(void* const* d_in, const int* in_sizes, int n_in,
                              void* d_out, int out_size, void* d_ws, size_t ws_size,
                              hipStream_t stream)
{
    const int*   X  = (const int*)d_in[0];
    const int*   Y  = (const int*)d_in[1];
    const float* lw = (const float*)d_in[2];
    const float* gw = (const float*)d_in[3];
    const float* sw = (const float*)d_in[4];
    const float* pw = (const float*)d_in[5];
    float* out = (float*)d_out;

    const int B = in_sizes[0] / 4;   // 65536
    const int T = in_sizes[1] / B;   // 512

    const int threads = 256;
    const int blocks = B / threads;  // B % 256 == 0
    bkt_fwd<<<blocks, threads, 0, stream>>>(X, Y, lw, gw, sw, pw, out, B, T);
}

// Round 10
// 82.710 us; speedup vs baseline: 1.1633x; 1.1633x over previous
//
#include <hip/hip_runtime.h>
#include <cmath>

// BKT forward, B independent students, serial T-step fp32 recurrence.
//
// NUMERICS (R1-R3): harness validates vs fp32 numpy recompute; recurrence
// amplifies rounding ~2e5x over 512 steps -> must replicate np's fp32 op
// order exactly (no FMA contraction, separate rounded mul/add/div, fp64
// sigmoid rounded once). Passing absmax = 0.0039. DO NOT reassociate.
//
// PERF history:
//  R3: per-step scattered stores -> WRITE 1.05 GB (3.9x), 268 us
//  R4: reg-buffered stores, compiler sank them (VGPR=32) -> 437 MB, 153 us
//  R5: __launch_bounds__(256,1) freed regs -> 122 us
//  R6: LDS-transpose store phase, full 128B-line stores -> 90 us
//  R7: STEPS 64 (page-activation theory) -> 90.5 us NULL. Refuted.
//  R8: fine-grained store interleave -> 96 us. REGRESSED; refuted.
//  R9/R10 (this): phase-separated streams. y>0 is 1 bit: pack each thread's
//      2KB y row into 16 u32 regs UP FRONT (pure-read phase, ~21us), then
//      the main loop issues ZERO global reads -> pure-write stream (memset
//      regime, measured 7.0 TB/s) with no read-under-write-pressure stalls
//      and no read/write turnaround. Chunk o's 32 bits = yp[0], rotated
//      down by static 15-mov shuffle per chunk (no dynamic reg indexing).
//      Stores: R6's proven LDS-transpose + nontemporal hint (out never
//      re-read; keep the 268MB store stream out of L2).
//      R10 fix: __builtin_nontemporal_store needs a NATIVE vector type,
//      not HIP_vector_type<float,4> -> use ext_vector_type(4) alias.

#define LSTR 36   // LDS row stride in floats: slot-bank = (9*lane+q)&31, bijective

typedef float floatx4 __attribute__((ext_vector_type(4)));

__global__ __launch_bounds__(256, 1) void bkt_fwd(
    const int* __restrict__ X,          // (B,4) int32 indices
    const int* __restrict__ Y,          // (B,T) int32 observations {0,1}
    const float* __restrict__ learn_w,  // (N,1)
    const float* __restrict__ guess_w,
    const float* __restrict__ slip_w,
    const float* __restrict__ prior_w,
    float* __restrict__ out,            // corrects (B,T) then latents (B,T)
    int B, int T)                       // requires B % 256 == 0, T == 512
{
#pragma clang fp contract(off)
    const int tid = threadIdx.x;
    const int b = blockIdx.x * 256 + tid;

    __shared__ float xp[256 * LSTR];    // 36.9 KB transpose buffer

    const int4 xi = *reinterpret_cast<const int4*>(X + (size_t)b * 4);
    // correctly-rounded fp32 sigmoids via fp64
    const float l = (float)(1.0 / (1.0 + exp(-(double)learn_w[xi.x])));
    const float g = (float)(1.0 / (1.0 + exp(-(double)guess_w[xi.y])));
    const float s = (float)(1.0 / (1.0 + exp(-(double)slip_w[xi.z])));
    const float p = (float)(1.0 / (1.0 + exp(-(double)prior_w[xi.w])));

    const float oms = 1.0f - s;              // (1-s)
    const float omg = 1.0f - g;              // (1-g)
    const float lo  = 1e-6f;
    const float hi  = (float)(1.0 - 1e-6);   // fp32(1-EPS)
    float latent = p;

    // ---- phase 0: pure-read. Pack own y row (T=512) into 16 u32 ----
    const int4* __restrict__ yv = reinterpret_cast<const int4*>(Y + (size_t)b * T);
    unsigned int yp[16];
    #pragma unroll
    for (int w = 0; w < 16; ++w) {
        unsigned int m = 0;
        #pragma unroll
        for (int q = 0; q < 8; ++q) {        // 8 int4 = 32 y values per word
            const int4 v = yv[w * 8 + q];
            m |= (v.x > 0 ? 1u : 0u) << (q * 4 + 0);
            m |= (v.y > 0 ? 1u : 0u) << (q * 4 + 1);
            m |= (v.z > 0 ? 1u : 0u) << (q * 4 + 2);
            m |= (v.w > 0 ? 1u : 0u) << (q * 4 + 3);
        }
        yp[w] = m;
    }

    // transpose-store mapping (R6, proven): instr q covers rows wv*64+q*8+r8,
    // 8 lanes per row covering the row's full 128B chunk.
    const int wv = tid >> 6, ln = tid & 63;
    const int r8 = ln >> 3, c8 = ln & 7;
    float* __restrict__ lrow = xp + tid * LSTR;
    const float* __restrict__ lrd = xp + (wv * 64 + r8) * LSTR + c8 * 4;
    float* __restrict__ gco = out + (size_t)(blockIdx.x * 256 + wv * 64 + r8) * T + c8 * 4;
    float* __restrict__ gla = gco + (size_t)B * T;

    constexpr int STEPS = 32, NQ = 8;
    const int nOuter = T / STEPS;            // 16

    // ---- main loop: pure-write ----
    for (int o = 0; o < nOuter; ++o) {
        const unsigned int ycur = yp[0];     // bits for t = o*32 .. o*32+31

        float cr[STEPS], lt[STEPS];
        #pragma unroll
        for (int j = 0; j < STEPS; ++j) {    // fully unrolled: static indexing
            // every statement = one IEEE fp32 rounding, np's association order
            const float a       = latent * oms;       // latent*(1-s)
            const float omlat   = 1.0f - latent;      // (1-latent)
            const float t1      = omlat * g;          // (1-latent)*g
            const float correct = a + t1;
            const float n0      = latent * s;         // latent*s
            const float t2      = omlat * omg;        // (1-latent)*(1-g)
            const float d0      = n0 + t2;
            const bool hit = (ycur >> j) & 1u;        // y_t > 0.5
            const float num = hit ? a : n0;
            const float den = hit ? correct : d0;
            const float k   = num / den;              // IEEE fp32 divide
            cr[j] = correct;
            lt[j] = latent;                           // recorded BEFORE update
            const float omk = 1.0f - k;
            const float t3  = omk * l;                // (1-k)*l
            const float nxt = k + t3;                 // k + (1-k)*l
            latent = fminf(fmaxf(nxt, lo), hi);       // clip
        }

        const int colo = o * STEPS;

        // ---- corrects: regs -> LDS row -> dense full-line global stores ----
        #pragma unroll
        for (int q = 0; q < NQ; ++q)
            *reinterpret_cast<float4*>(lrow + q * 4) =
                make_float4(cr[4*q], cr[4*q+1], cr[4*q+2], cr[4*q+3]);
        __builtin_amdgcn_wave_barrier();   // order ds_write before ds_read
        #pragma unroll
        for (int q = 0; q < NQ; ++q) {
            const floatx4 v = *reinterpret_cast<const floatx4*>(lrd + (q * 8) * LSTR);
            __builtin_nontemporal_store(v,
                reinterpret_cast<floatx4*>(gco + (size_t)(q * 8) * T + colo));
        }
        __builtin_amdgcn_wave_barrier();   // order reads before lt-pass overwrite

        // ---- latents ----
        #pragma unroll
        for (int q = 0; q < NQ; ++q)
            *reinterpret_cast<float4*>(lrow + q * 4) =
                make_float4(lt[4*q], lt[4*q+1], lt[4*q+2], lt[4*q+3]);
        __builtin_amdgcn_wave_barrier();
        #pragma unroll
        for (int q = 0; q < NQ; ++q) {
            const floatx4 v = *reinterpret_cast<const floatx4*>(lrd + (q * 8) * LSTR);
            __builtin_nontemporal_store(v,
                reinterpret_cast<floatx4*>(gla + (size_t)(q * 8) * T + colo));
        }
        __builtin_amdgcn_wave_barrier();

        // rotate packed-y words down (static indices only)
        #pragma unroll
        for (int w = 0; w < 15; ++w) yp[w] = yp[w + 1];
    }
}

extern "C" void kernel_launch(void* const* d_in, const int* in_sizes, int n_in,
                              void* d_out, int out_size, void* d_ws, size_t ws_size,
                              hipStream_t stream)
{
    const int*   X  = (const int*)d_in[0];
    const int*   Y  = (const int*)d_in[1];
    const float* lw = (const float*)d_in[2];
    const float* gw = (const float*)d_in[3];
    const float* sw = (const float*)d_in[4];
    const float* pw = (const float*)d_in[5];
    float* out = (float*)d_out;

    const int B = in_sizes[0] / 4;   // 65536
    const int T = in_sizes[1] / B;   // 512

    const int threads = 256;
    const int blocks = B / threads;  // B % 256 == 0
    bkt_fwd<<<blocks, threads, 0, stream>>>(X, Y, lw, gw, sw, pw, out, B, T);
}